// Round 16
// baseline (331.517 us; speedup 1.0000x reference)
//
#include <hip/hip_runtime.h>
#include <math.h>

// ---------------------------------------------------------------------------
// SwinV2 block, fused bf16-MFMA. R28 = R27 (326.5us) + two final levers:
//  - s_setprio(1) around every MFMA cluster (QKV, S^T, PV, proj, G1, G2).
//    T5 catalog: pays when co-resident waves have role diversity (attn
//    +4-7%, lockstep GEMM null). Our 12 waves/CU from 3 blocks are phase-
//    staggered by the R23-R27 fillers -> scheduler can favor MFMA-entering
//    waves while others run softmax/GELU VALU. Pure hint, zero risk.
//  - n2w/n2b (LN2 params) prefetched in MLP chunk-3's idle b1-prefetch slot
//    (last uncovered phase-entry window, ~250cy hidden under G2(3)).
// Math order per value unchanged -> absmax canary 0.09375.
// Evidence: R23 -6%, R24 -2%, R25 -1%, R26 -4%, R27 -2%; filler windows now
// all covered; VALU-busy total ~156us is the structural floor component.
// MFMA 16x16x32 bf16: A[m][k]: m=l15,k=lg*8+i ; B[k][n]: n=l15,k=lg*8+i
//                     C[m][n]: n=l15, m=lg*4+r   (validated rounds 2-27)
// ---------------------------------------------------------------------------

constexpr int WIN=8, CD=96, RH=128, RW=128, SHF=4;

// LDS layout in shorts
constexpr int KN_S=40, VT_S=72, WB_S=104;
constexpr int OFF_KN=0;                 // kn [64][40]            0..2560
constexpr int OFF_VT=2560;              // vt [32][72]            ..4864
constexpr int PAN_SH=10240;             // padded panel: 96*104 (+256 pad) shorts
constexpr int OFF_WB0=4864;             // panel buf0             ..15104
constexpr int OFF_WB1=15104;            // panel buf1             ..25344
constexpr int LDS_SHORTS=25344;
constexpr int LDS_BYTES = LDS_SHORTS*2; // 50688 B -> 3 blocks/CU

typedef float f32x4 __attribute__((ext_vector_type(4)));
typedef short s16x8 __attribute__((ext_vector_type(8)));
typedef short s16x4 __attribute__((ext_vector_type(4)));
typedef int   i32x2 __attribute__((ext_vector_type(2)));
typedef int   i32x4 __attribute__((ext_vector_type(4)));
typedef unsigned int u32x2 __attribute__((ext_vector_type(2)));

#define MFMA16(a,b,c) __builtin_amdgcn_mfma_f32_16x16x32_bf16((a),(b),(c),0,0,0)
#define PRIO_HI() __builtin_amdgcn_s_setprio(1)
#define PRIO_LO() __builtin_amdgcn_s_setprio(0)

#if __has_builtin(__builtin_amdgcn_permlane32_swap) && __has_builtin(__builtin_amdgcn_permlane16_swap)
#define HAVE_PLSWAP 1
#else
#define HAVE_PLSWAP 0
#endif

// raw hardware 2^x (v_exp_f32). exp2f() is the precise libm version with
// multi-op edge handling -- see R25 post-mortem (VALUBusy 45->57%).
__device__ __forceinline__ float fexp2(float x) {
#if __has_builtin(__builtin_amdgcn_exp2f)
    return __builtin_amdgcn_exp2f(x);
#else
    return exp2f(x);
#endif
}

// RAW barrier without the implicit vmcnt(0) drain (panel prefetch stays
// in flight). lgkmcnt(0): this wave's ds_writes complete; s_barrier: sync.
#define RAW_LDS_BARRIER() do { \
    asm volatile("s_waitcnt lgkmcnt(0)" ::: "memory"); \
    __builtin_amdgcn_s_barrier(); \
    asm volatile("" ::: "memory"); } while (0)

__device__ __forceinline__ short f2bf(float f) {
    __bf16 b = (__bf16)f;
    return __builtin_bit_cast(short, b);
}
__device__ __forceinline__ s16x8 ld8(const short* p) {
    return *reinterpret_cast<const s16x8*>(p);
}
__device__ __forceinline__ s16x4 pack4(float a, float b, float c, float d) {
    s16x4 r; r[0]=f2bf(a); r[1]=f2bf(b); r[2]=f2bf(c); r[3]=f2bf(d);
    return r;
}
__device__ __forceinline__ s16x8 abf_from_f32(const float* p) {
    const f32x4* q = reinterpret_cast<const f32x4*>(p);
    f32x4 a = q[0], b = q[1];
    s16x8 r;
    r[0]=f2bf(a[0]); r[1]=f2bf(a[1]); r[2]=f2bf(a[2]); r[3]=f2bf(a[3]);
    r[4]=f2bf(b[0]); r[5]=f2bf(b[1]); r[6]=f2bf(b[2]); r[7]=f2bf(b[3]);
    return r;
}

#if HAVE_PLSWAP
__device__ __forceinline__ void plswap32(unsigned &a, unsigned &b) {
    u32x2 r = __builtin_amdgcn_permlane32_swap(a, b, false, false);
    a = r[0]; b = r[1];
}
__device__ __forceinline__ void plswap16(unsigned &a, unsigned &b) {
    u32x2 r = __builtin_amdgcn_permlane16_swap(a, b, false, false);
    a = r[0]; b = r[1];
}
#endif

// wave-local lg-transpose: p0,p1 hold v[base+{0,16}+lg*4+rr] (packed bf16);
// returns B-fragment f[i] = v[base+lg*8+i] for this lane's lg.
__device__ __forceinline__ s16x8 xposeT(s16x4 p0, s16x4 p1, int l) {
    i32x2 q0 = __builtin_bit_cast(i32x2, p0);
    i32x2 q1 = __builtin_bit_cast(i32x2, p1);
#if HAVE_PLSWAP
    (void)l;
    unsigned a0 = (unsigned)q0[0], a1 = (unsigned)q0[1];
    unsigned b0 = (unsigned)q1[0], b1 = (unsigned)q1[1];
    plswap32(a0, b0);
    plswap32(a1, b1);
    plswap16(a0, b0);
    plswap16(a1, b1);
    i32x4 w; w[0]=(int)a0; w[1]=(int)a1; w[2]=(int)b0; w[3]=(int)b1;
    return __builtin_bit_cast(s16x8, w);
#else
    const int l15 = l & 15, lg = l >> 4;
    const int L1 = l15 + (((2*lg  )&3)<<4);
    const int L2 = l15 + (((2*lg+1)&3)<<4);
    const bool lo = (lg & 2) == 0;
    int a0 = __shfl(q0[0], L1), b0 = __shfl(q1[0], L1);
    int a1 = __shfl(q0[1], L1), b1 = __shfl(q1[1], L1);
    int a2 = __shfl(q0[0], L2), b2 = __shfl(q1[0], L2);
    int a3 = __shfl(q0[1], L2), b3 = __shfl(q1[1], L2);
    i32x4 w;
    w[0] = lo ? a0 : b0;
    w[1] = lo ? a1 : b1;
    w[2] = lo ? a2 : b2;
    w[3] = lo ? a3 : b3;
    return __builtin_bit_cast(s16x8, w);
#endif
}
// reduce across the 4 lg groups (lanes sharing l15), VALU pipe when possible
__device__ __forceinline__ float xsum4(float v) {
#if HAVE_PLSWAP
    unsigned a = __builtin_bit_cast(unsigned, v), b = a;
    plswap16(a, b);
    float s = __builtin_bit_cast(float, a) + __builtin_bit_cast(float, b);
    unsigned c = __builtin_bit_cast(unsigned, s), d = c;
    plswap32(c, d);
    return __builtin_bit_cast(float, c) + __builtin_bit_cast(float, d);
#else
    v += __shfl_xor(v,16); v += __shfl_xor(v,32); return v;
#endif
}
__device__ __forceinline__ float xmax4(float v) {
#if HAVE_PLSWAP
    unsigned a = __builtin_bit_cast(unsigned, v), b = a;
    plswap16(a, b);
    float s = fmaxf(__builtin_bit_cast(float, a), __builtin_bit_cast(float, b));
    unsigned c = __builtin_bit_cast(unsigned, s), d = c;
    plswap32(c, d);
    return fmaxf(__builtin_bit_cast(float, c), __builtin_bit_cast(float, d));
#else
    v = fmaxf(v, __shfl_xor(v,16)); v = fmaxf(v, __shfl_xor(v,32)); return v;
#endif
}
__device__ __forceinline__ int region_id(int hh, int ww) {
    int rr = (hh < RH-WIN) ? 0 : ((hh < RH-SHF) ? 1 : 2);
    int rc = (ww < RW-WIN) ? 0 : ((ww < RW-SHF) ? 1 : 2);
    return rr*3 + rc;
}
// GELU with log2e folded into the polynomial (raw v_exp_f32)
__device__ __forceinline__ float gelu_f(float h) {
    float u = h * (2.3022089f + 0.10294356f * h * h);
    float e = fexp2(-u);
    return h * __builtin_amdgcn_rcpf(1.f + e);
}

// async stage of one padded 20480-B panel into LDS (linear dest, 20 chunks)
__device__ __forceinline__ void stage_panel(const short* __restrict__ pan,
                                            short* dst, int wv, int l) {
    const char* g = (const char*)pan + l*16;
    char* d = (char*)dst;
    #pragma unroll
    for (int k = 0; k < 5; ++k) {
        int i = wv + k*4;                 // exactly 20 chunks of 1024 B / 4 waves
        __builtin_amdgcn_global_load_lds(
            (const __attribute__((address_space(1))) unsigned int*)(g + i*1024),
            (__attribute__((address_space(3))) unsigned int*)(d + i*1024),
            16, 0, 0);
    }
}

// ---------------------------------------------------------------------------
__global__ __launch_bounds__(256) void cpb_kernel(
    const float* __restrict__ w1, const float* __restrict__ b1,
    const float* __restrict__ w2, float* __restrict__ rpb)
{
    int g = blockIdx.x*256 + threadIdx.x;
    if (g >= 225*3) return;
    int e = g/3, h = g - e*3;
    int a = e/15, bb = e - a*15;
    float z0 = (float)(a-7) * (8.0f/7.0f);
    float z1 = (float)(bb-7) * (8.0f/7.0f);
    float s0 = (z0>0.f)?1.f:((z0<0.f)?-1.f:0.f);
    float s1 = (z1>0.f)?1.f:((z1<0.f)?-1.f:0.f);
    float t0 = s0 * log2f(fabsf(z0)+1.f) * (1.f/3.f);
    float t1 = s1 * log2f(fabsf(z1)+1.f) * (1.f/3.f);
    float acc = 0.f;
    for (int k = 0; k < 512; ++k) {
        float hv = t0*w1[2*k] + t1*w1[2*k+1] + b1[k];
        hv = fmaxf(hv, 0.f);
        acc += hv * w2[h*512 + k];
    }
    rpb[g] = 16.f / (1.f + __expf(-acc));
}

// biasT pre-scaled by log2e (softmax computed in exp2 domain)
__global__ __launch_bounds__(256) void biasbuild_kernel(
    const float* __restrict__ rpb, float* __restrict__ biasT)
{
    int g = blockIdx.x*256 + threadIdx.x;     // 12288
    if (g >= 3*64*64) return;
    int h = g >> 12, rem = g & 4095, i = rem >> 6, j = rem & 63;
    int ih = i>>3, iw = i&7, jh = j>>3, jw = j&7;
    int idx = (ih-jh+7)*15 + (iw-jw+7);
    biasT[g] = rpb[idx*3 + h] * 1.44269504f;
}

// prepack 12 padded panels (rows of WB_S=104 shorts, 96 valid cols)
__global__ __launch_bounds__(256) void wcvt_kernel(
    const float* __restrict__ qkvw, const float* __restrict__ projw,
    const float* __restrict__ w1,   const float* __restrict__ w2,
    short* __restrict__ wpan)
{
    int i = blockIdx.x*256 + threadIdx.x;     // 110592 exact (432 blocks)
    if (i >= 12*9216) return;
    int p = i / 9216;
    int rem = i - p*9216;
    int r = rem / 96;
    int col = rem - r*96;
    float v;
    if (p < 3)        v = qkvw[((r>>5)*96 + p*32 + (r&31))*96 + col];
    else if (p == 3)  v = projw[r*96 + col];
    else if (((p-4)&1) == 0) { int c = (p-4)>>1; v = w1[(c*96 + r)*96 + col]; }
    else              { int c = (p-4)>>1; v = w2[r*384 + c*96 + col]; }
    wpan[p*PAN_SH + r*WB_S + col] = f2bf(v);
}

// ---------------------------------------------------------------------------
__global__ __launch_bounds__(256,3) void fused_kernel(
    const float* __restrict__ x,
    const float* __restrict__ n1w, const float* __restrict__ n1b,
    const float* __restrict__ qb,  const float* __restrict__ vb,
    const float* __restrict__ lgs, const float* __restrict__ pb,
    const float* __restrict__ n2w, const float* __restrict__ n2b,
    const float* __restrict__ b1,  const float* __restrict__ b2,
    const float* __restrict__ biasT,
    const short* __restrict__ wpan,   // 12 padded panels
    float* __restrict__ out)
{
    extern __shared__ __align__(16) short smem[];
    short* kn  = smem + OFF_KN;
    short* vt  = smem + OFF_VT;
    short* wb0 = smem + OFF_WB0;
    short* wb1 = smem + OFF_WB1;

    const int t = threadIdx.x;
    const int l = t & 63;
    const int wv = t >> 6;
    const int l15 = l & 15;
    const int lg  = l >> 4;

    const int wid = blockIdx.x;
    const int b = wid >> 8, wi = wid & 255, wh = wi >> 4, ww = wi & 15;
    const float* xb = x + (size_t)b * (RH*RW*CD);

    // lane's own token and its global (gather == scatter) position
    const int arow = wv*16 + l15;
    const int ahs = (wh*WIN + (arow>>3) + SHF) & (RH-1);
    const int aws = (ww*WIN + (arow&7)  + SHF) & (RW-1);
    const unsigned go = ((unsigned)(b << 14) + ahs*RW + aws) * CD;
    const float* xrow = xb + (ahs*RW + aws)*CD;
    s16x8 xa[3];
    #pragma unroll
    for (int kt = 0; kt < 3; ++kt) xa[kt] = abf_from_f32(xrow + kt*32 + lg*8);

    // shift-mask (log2e-scaled, exp2 domain): i = arow, j = mt*16+lg*4+rr
    f32x4 maskv[4];
    {
        int regi = region_id(wh*WIN + (arow>>3), ww*WIN + (arow&7));
        #pragma unroll
        for (int mt = 0; mt < 4; ++mt)
            #pragma unroll
            for (int rr = 0; rr < 4; ++rr) {
                int j = mt*16 + lg*4 + rr;
                int regj = region_id(wh*WIN + (j>>3), ww*WIN + (j&7));
                maskv[mt][rr] = (regi != regj) ? -144.2695041f : 0.f;
            }
    }

    // head-0 S^T C-in (bias+mask) prefetched before any barrier
    f32x4 bvmc[4], bvmn[4];
    {
        const float* bh = biasT + arow*64;
        #pragma unroll
        for (int mt = 0; mt < 4; ++mt) {
            f32x4 bv = *reinterpret_cast<const f32x4*>(bh + mt*16 + lg*4);
            #pragma unroll
            for (int rr = 0; rr < 4; ++rr) bvmc[mt][rr] = bv[rr] + maskv[mt][rr];
        }
    }

    // QKV compute: reads weight panel (LDS) + xa regs; biases as C-in.
    auto qkv_compute = [&](const short* wbuf, int hh,
                           f32x4 qc[2], f32x4 kc[2], f32x4 vc[2]) {
        PRIO_HI();
        #pragma unroll
        for (int sec = 0; sec < 3; ++sec) {
            #pragma unroll
            for (int nt = 0; nt < 2; ++nt) {
                f32x4 c;
                if (sec==0)      c = *reinterpret_cast<const f32x4*>(qb + hh*32 + nt*16 + lg*4);
                else if (sec==2) c = *reinterpret_cast<const f32x4*>(vb + hh*32 + nt*16 + lg*4);
                else             c = (f32x4){0.f,0.f,0.f,0.f};
                const short* wp = wbuf + (sec*32 + nt*16 + l15)*WB_S;
                #pragma unroll
                for (int kt = 0; kt < 3; ++kt)
                    c = MFMA16(ld8(wp + kt*32 + lg*8), xa[kt], c);
                if (sec==0) qc[nt]=c; else if (sec==1) kc[nt]=c; else vc[nt]=c;
            }
        }
        PRIO_LO();
    };
    // norms over d (paired trees + cross-group reduce); scq carries log2e
    auto qk_norms = [&](const f32x4 qc[2], const f32x4 kc[2], int hh,
                        float &scq, float &sck) {
        float sq = ((qc[0][0]*qc[0][0] + qc[0][1]*qc[0][1])
                  + (qc[0][2]*qc[0][2] + qc[0][3]*qc[0][3]))
                 + ((qc[1][0]*qc[1][0] + qc[1][1]*qc[1][1])
                  + (qc[1][2]*qc[1][2] + qc[1][3]*qc[1][3]));
        float sk = ((kc[0][0]*kc[0][0] + kc[0][1]*kc[0][1])
                  + (kc[0][2]*kc[0][2] + kc[0][3]*kc[0][3]))
                 + ((kc[1][0]*kc[1][0] + kc[1][1]*kc[1][1])
                  + (kc[1][2]*kc[1][2] + kc[1][3]*kc[1][3]));
        sq = xsum4(sq);
        sk = xsum4(sk);
        float ls = 1.44269504f * __expf(fminf(lgs[hh], 4.60517019f));
        scq = ls * __builtin_amdgcn_rsqf(fmaxf(sq, 1e-24f));
        sck =      __builtin_amdgcn_rsqf(fmaxf(sk, 1e-24f));
    };

    // ================= prologue: P0,P1 staged; QKV(0); knvt(0) =================
    stage_panel(wpan,          wb0, wv, l);            // P0 -> buf0 (async)
    stage_panel(wpan + PAN_SH, wb1, wv, l);            // P1 -> buf1 (async)
    __syncthreads();                                   // drain P0+P1

    s16x4 qp0, qp1;                                    // head-h q packed
    {
        f32x4 qc[2], kc[2], vc[2];
        qkv_compute(wb0, 0, qc, kc, vc);
        float scq, sck;
        qk_norms(qc, kc, 0, scq, sck);
        qp0 = pack4(qc[0][0]*scq, qc[0][1]*scq, qc[0][2]*scq, qc[0][3]*scq);
        qp1 = pack4(qc[1][0]*scq, qc[1][1]*scq, qc[1][2]*scq, qc[1][3]*scq);
        #pragma unroll
        for (int nt = 0; nt < 2; ++nt) {
            *reinterpret_cast<s16x4*>(kn + arow*KN_S + nt*16 + lg*4) =
                pack4(kc[nt][0]*sck, kc[nt][1]*sck, kc[nt][2]*sck, kc[nt][3]*sck);
            #pragma unroll
            for (int rr = 0; rr < 4; ++rr)
                vt[(nt*16 + lg*4 + rr)*VT_S + arow] = f2bf(vc[nt][rr]);
        }
    }
    RAW_LDS_BARRIER();                                 // knvt(0) visible

    s16x4 aop[6];                                      // attn out, packed bf16
    f32x4 xv6[6];                                      // x residual (head-2 prefetch)
    f32x4 pbv[6];                                      // proj bias (head-2 prefetch)
    f32x4 nw1v[6], nb1v[6];                            // LN1 w/b (head-2 prefetch)
    s16x8 aB[3];                                       // proj A-fragments

    // ================= attention heads (software-pipelined) =================
    #pragma unroll
    for (int h = 0; h < 3; ++h) {
        // stage P(h+2): wb[h&1]'s readers (QKV(h)) all passed the last
        // s_barrier (WAR safe). Drained by a later full __syncthreads().
        stage_panel(wpan + (h+2)*PAN_SH, (h&1) ? wb1 : wb0, wv, l);

        // ---- S^T = mfma(kn, qA, bias+mask prefetched): C[m=j][n=i=arow] ----
        s16x8 qA = xposeT(qp0, qp1, l);
        f32x4 st[4];
        PRIO_HI();
        #pragma unroll
        for (int mt = 0; mt < 4; ++mt)
            st[mt] = MFMA16(ld8(kn + (mt*16 + l15)*KN_S + lg*8), qA, bvmc[mt]);
        PRIO_LO();

        // ---- PIPELINE filler for the softmax dependency-stall window ----
        f32x4 nqc[2], nkc[2], nvc[2];
        if (h < 2) {
            // QKV(h+1) compute (independent of kn/vt) + bvm(h+1) prefetch
            qkv_compute((h&1) ? wb0 : wb1, h+1, nqc, nkc, nvc);
            const float* bh2 = biasT + (h+1)*4096 + arow*64;
            #pragma unroll
            for (int mt = 0; mt < 4; ++mt) {
                f32x4 bv = *reinterpret_cast<const f32x4*>(bh2 + mt*16 + lg*4);
                #pragma unroll
                for (int rr = 0; rr < 4; ++rr) bvmn[mt][rr] = bv[rr] + maskv[mt][rr];
            }
        } else {
            // head 2: issue x-residual + proj-bias + LN1 w/b loads (consumed
            // at proj/LN1; only RAW barriers -- no vmcnt drain -- between
            // here and use) + proj A-fragment xposes for heads 0/1.
            #pragma unroll
            for (int nt = 0; nt < 6; ++nt) {
                xv6[nt]  = *reinterpret_cast<const f32x4*>(x + go + nt*16 + lg*4);
                pbv[nt]  = *reinterpret_cast<const f32x4*>(pb + nt*16 + lg*4);
                nw1v[nt] = *reinterpret_cast<const f32x4*>(n1w + nt*16 + lg*4);
                nb1v[nt] = *reinterpret_cast<const f32x4*>(n1b + nt*16 + lg*4);
            }
            aB[0] = xposeT(aop[0], aop[1], l);
            aB[1] = xposeT(aop[2], aop[3], l);
        }

        // ---- softmax over j (exp2 domain, raw v_exp_f32) ----
        float m0 = fmaxf(fmaxf(st[0][0],st[0][1]), fmaxf(st[0][2],st[0][3]));
        float m1 = fmaxf(fmaxf(st[1][0],st[1][1]), fmaxf(st[1][2],st[1][3]));
        float m2 = fmaxf(fmaxf(st[2][0],st[2][1]), fmaxf(st[2][2],st[2][3]));
        float m3 = fmaxf(fmaxf(st[3][0],st[3][1]), fmaxf(st[3][2],st[3][3]));
        float mx = xmax4(fmaxf(fmaxf(m0,m1), fmaxf(m2,m3)));
        float sp[4];
        #pragma unroll
        for (int mt = 0; mt < 4; ++mt) {
            #pragma unroll
            for (int rr = 0; rr < 4; ++rr)
                st[mt][rr] = fexp2(st[mt][rr] - mx);
            sp[mt] = (st[mt][0] + st[mt][1]) + (st[mt][2] + st[mt][3]);
        }
        float sm = xsum4((sp[0] + sp[1]) + (sp[2] + sp[3]));
        float inv = __builtin_amdgcn_rcpf(sm);

        // ---- retire head h+1 norms EARLY (independent of P; shortens the
        //      post-PV tail before the convoy-limiting __syncthreads) ----
        float sck_n = 0.f;
        s16x4 nq0, nq1;
        if (h < 2) {
            float scq_n;
            qk_norms(nqc, nkc, h+1, scq_n, sck_n);
            nq0 = pack4(nqc[0][0]*scq_n, nqc[0][1]*scq_n, nqc[0][2]*scq_n, nqc[0][3]*scq_n);
            nq1 = pack4(nqc[1][0]*scq_n, nqc[1][1]*scq_n, nqc[1][2]*scq_n, nqc[1][3]*scq_n);
        }

        // ---- P packed UNNORMALIZED; inv folded into aop pack ----
        s16x4 pw[4];
        #pragma unroll
        for (int mt = 0; mt < 4; ++mt)
            pw[mt] = pack4(st[mt][0], st[mt][1], st[mt][2], st[mt][3]);

        // ---- PV^T = mfma(vt, P-frag): C[m=d][n=token] -> packed regs ----
        s16x8 pB0 = xposeT(pw[0], pw[1], l);
        s16x8 pB1 = xposeT(pw[2], pw[3], l);
        PRIO_HI();
        #pragma unroll
        for (int nt2 = 0; nt2 < 2; ++nt2) {
            f32x4 o = {0.f,0.f,0.f,0.f};
            o = MFMA16(ld8(vt + (nt2*16+l15)*VT_S + 0  + lg*8), pB0, o);
            o = MFMA16(ld8(vt + (nt2*16+l15)*VT_S + 32 + lg*8), pB1, o);
            aop[h*2 + nt2] = pack4(o[0]*inv, o[1]*inv, o[2]*inv, o[3]*inv);
        }
        PRIO_LO();

        // ---- retire: barrier, then knvt(h+1) writes ----
        if (h < 2) {
            __syncthreads();               // all waves' S/PV(h) kn/vt reads done;
                                           // also drains P(h+2) (full phase old)
            #pragma unroll
            for (int nt = 0; nt < 2; ++nt) {
                *reinterpret_cast<s16x4*>(kn + arow*KN_S + nt*16 + lg*4) =
                    pack4(nkc[nt][0]*sck_n, nkc[nt][1]*sck_n,
                          nkc[nt][2]*sck_n, nkc[nt][3]*sck_n);
                #pragma unroll
                for (int rr = 0; rr < 4; ++rr)
                    vt[(nt*16 + lg*4 + rr)*VT_S + arow] = f2bf(nvc[nt][rr]);
            }
            RAW_LDS_BARRIER();             // knvt(h+1) visible; panel stage
                                           // stays in flight (no vmcnt drain)
            qp0 = nq0; qp1 = nq1;
            #pragma unroll
            for (int mt = 0; mt < 4; ++mt) bvmc[mt] = bvmn[mt];
        }
    }

    // ================= proj^T + LN1 + residual (in-register) =================
    // P3 (proj) landed in wb1 (staged iter1, drained at iter1's syncthreads);
    // P4 (w1 c0) staged at iter2 top, drains at the MLP-top syncthreads.
    aB[2] = xposeT(aop[4], aop[5], l);
    f32x4 pc[6];
    PRIO_HI();
    #pragma unroll
    for (int nt = 0; nt < 6; ++nt) {
        f32x4 c = pbv[nt];                             // prefetched proj bias
        const short* wp = wb1 + (nt*16 + l15)*WB_S;
        #pragma unroll
        for (int kt = 0; kt < 3; ++kt)
            c = MFMA16(ld8(wp + kt*32 + lg*8), aB[kt], c);
        pc[nt] = c;                                    // C[m=outc][n=token=arow]
    }
    PRIO_LO();

    f32x4 x1v[6];                                      // f32 residual in regs
    s16x4 x1p[6];                                      // packed bf16 x1
    {
        float sA=0.f, sB=0.f, s2A=0.f, s2B=0.f;
        #pragma unroll
        for (int nt = 0; nt < 6; ++nt) {
            f32x4 v = pc[nt];
            float ps  = (v[0]+v[1]) + (v[2]+v[3]);
            float ps2 = (v[0]*v[0]+v[1]*v[1]) + (v[2]*v[2]+v[3]*v[3]);
            if (nt & 1) { sB += ps; s2B += ps2; } else { sA += ps; s2A += ps2; }
        }
        float s = xsum4(sA + sB), s2 = xsum4(s2A + s2B);
        float mu  = s * (1.f/96.f);
        float var = s2 * (1.f/96.f) - mu*mu;
        float rstd = __builtin_amdgcn_rsqf(var + 1e-5f);
        #pragma unroll
        for (int nt = 0; nt < 6; ++nt) {
            f32x4 v;
            #pragma unroll
            for (int rr = 0; rr < 4; ++rr)
                v[rr] = xv6[nt][rr] + (pc[nt][rr] - mu)*rstd*nw1v[nt][rr] + nb1v[nt][rr];
            x1v[nt] = v;
            x1p[nt] = pack4(v[0], v[1], v[2], v[3]);
        }
    }

    // ================= MLP (swapped G1/G2, in-register h) =================
    s16x8 x1B[3];
    #pragma unroll
    for (int kt = 0; kt < 3; ++kt)
        x1B[kt] = xposeT(x1p[2*kt], x1p[2*kt+1], l);

    f32x4 b1v[6];                                      // G1 C-in, chunk 0
    #pragma unroll
    for (int nt = 0; nt < 6; ++nt)
        b1v[nt] = *reinterpret_cast<const f32x4*>(b1 + nt*16 + lg*4);

    f32x4 oa[6];
    #pragma unroll
    for (int nt = 0; nt < 6; ++nt)                     // b2 as G2 C-in
        oa[nt] = *reinterpret_cast<const f32x4*>(b2 + nt*16 + lg*4);

    f32x4 nw2v[6], nb2v[6];                            // LN2 w/b (chunk-3 prefetch)

    for (int c = 0; c < 4; ++c) {
        __syncthreads();                    // w1 chunk landed (vmcnt WANTED)
        stage_panel(wpan + (5+2*c)*PAN_SH, wb1, wv, l);
        // G1^T: C[m=hid][n=token], prefetched b1 as C-in -> GELU -> packed
        s16x4 hp[6];
        PRIO_HI();
        #pragma unroll
        for (int nt = 0; nt < 6; ++nt) {
            f32x4 a = b1v[nt];
            const short* wp = wb0 + (nt*16 + l15)*WB_S;
            #pragma unroll
            for (int kt = 0; kt < 3; ++kt)
                a = MFMA16(ld8(wp + kt*32 + lg*8), x1B[kt], a);
            hp[nt] = pack4(gelu_f(a[0]), gelu_f(a[1]), gelu_f(a[2]), gelu_f(a[3]));
        }
        PRIO_LO();
        // prefetch b1 for next chunk (overlaps GELU; drained at next sync);
        // chunk 3: prefetch LN2 params instead (last uncovered window)
        if (c < 3) {
            #pragma unroll
            for (int nt = 0; nt < 6; ++nt)
                b1v[nt] = *reinterpret_cast<const f32x4*>(b1 + (c+1)*96 + nt*16 + lg*4);
        } else {
            #pragma unroll
            for (int nt = 0; nt < 6; ++nt) {
                nw2v[nt] = *reinterpret_cast<const f32x4*>(n2w + nt*16 + lg*4);
                nb2v[nt] = *reinterpret_cast<const f32x4*>(n2b + nt*16 + lg*4);
            }
        }
        __syncthreads();                    // w2 chunk landed (vmcnt WANTED)
        if (c < 3) stage_panel(wpan + (6+2*c)*PAN_SH, wb0, wv, l);
        // G2^T accumulate: C[m=outc][n=token]
        s16x8 hB[3];
        #pragma unroll
        for (int kt = 0; kt < 3; ++kt)
            hB[kt] = xposeT(hp[2*kt], hp[2*kt+1], l);
        PRIO_HI();
        #pragma unroll
        for (int nt = 0; nt < 6; ++nt) {
            const short* wp = wb1 + (nt*16 + l15)*WB_S;
            #pragma unroll
            for (int kt = 0; kt < 3; ++kt)
                oa[nt] = MFMA16(ld8(wp + kt*32 + lg*8), hB[kt], oa[nt]);
        }
        PRIO_LO();
    }

    // ---- LN2 (+b2 already in oa), +x1 residual, f32x4 stores ----
    {
        float sA=0.f, sB=0.f, s2A=0.f, s2B=0.f;
        #pragma unroll
        for (int nt = 0; nt < 6; ++nt) {
            f32x4 v = oa[nt];
            float ps  = (v[0]+v[1]) + (v[2]+v[3]);
            float ps2 = (v[0]*v[0]+v[1]*v[1]) + (v[2]*v[2]+v[3]*v[3]);
            if (nt & 1) { sB += ps; s2B += ps2; } else { sA += ps; s2A += ps2; }
        }
        float s = xsum4(sA + sB), s2 = xsum4(s2A + s2B);
        float mu  = s * (1.f/96.f);
        float var = s2 * (1.f/96.f) - mu*mu;
        float rstd = __builtin_amdgcn_rsqf(var + 1e-5f);
        #pragma unroll
        for (int nt = 0; nt < 6; ++nt) {
            f32x4 res;
            #pragma unroll
            for (int rr = 0; rr < 4; ++rr)
                res[rr] = x1v[nt][rr] + (oa[nt][rr] - mu)*rstd*nw2v[nt][rr] + nb2v[nt][rr];
            *reinterpret_cast<f32x4*>(out + go + nt*16 + lg*4) = res;
        }
    }
}

// ---------------------------------------------------------------------------
extern "C" void kernel_launch(void* const* d_in, const int* in_sizes, int n_in,
                              void* d_out, int out_size, void* d_ws, size_t ws_size,
                              hipStream_t stream) {
    const float* x       = (const float*)d_in[0];
    const float* norm1_w = (const float*)d_in[1];
    const float* norm1_b = (const float*)d_in[2];
    const float* qkv_w   = (const float*)d_in[3];
    const float* q_bias  = (const float*)d_in[4];
    const float* v_bias  = (const float*)d_in[5];
    const float* lgs     = (const float*)d_in[6];
    const float* cpb_w1  = (const float*)d_in[7];
    const float* cpb_b1  = (const float*)d_in[8];
    const float* cpb_w2  = (const float*)d_in[9];
    const float* proj_w  = (const float*)d_in[10];
    const float* proj_b  = (const float*)d_in[11];
    const float* norm2_w = (const float*)d_in[12];
    const float* norm2_b = (const float*)d_in[13];
    const float* mlp_w1  = (const float*)d_in[14];
    const float* mlp_b1  = (const float*)d_in[15];
    const float* mlp_w2  = (const float*)d_in[16];
    const float* mlp_b2  = (const float*)d_in[17];

    char* wsb = (char*)d_ws;
    float* rpbTab = (float*)wsb;                     // 675 f32   @ 0
    float* biasT  = (float*)(wsb + 4096);            // 12288 f32 @ 4096
    short* wpan   = (short*)(wsb + 53248);           // 12 padded panels (240 KB)

    float* out = (float*)d_out;

    hipFuncSetAttribute(reinterpret_cast<const void*>(fused_kernel),
                        hipFuncAttributeMaxDynamicSharedMemorySize, LDS_BYTES);

    cpb_kernel<<<3, 256, 0, stream>>>(cpb_w1, cpb_b1, cpb_w2, rpbTab);
    biasbuild_kernel<<<48, 256, 0, stream>>>(rpbTab, biasT);
    wcvt_kernel<<<432, 256, 0, stream>>>(qkv_w, proj_w, mlp_w1, mlp_w2, wpan);
    fused_kernel<<<8192, 256, LDS_BYTES, stream>>>(x, norm1_w, norm1_b,
                                                   q_bias, v_bias, lgs, proj_b,
                                                   norm2_w, norm2_b, mlp_b1, mlp_b2,
                                                   biasT, wpan, out);
}

// Round 17
// 321.784 us; speedup vs baseline: 1.0302x; 1.0302x over previous
//
#include <hip/hip_runtime.h>
#include <math.h>

// ---------------------------------------------------------------------------
// SwinV2 block, fused bf16-MFMA. R29 = R27 (326.5us, best) + ONLY the LN2
// param prefetch from R28 (setprio REVERTED).
// R28 post-mortem: setprio bundle regressed +1.5% (331.5us) -- consistent
// with T5's GEMM null/negative on barrier-convoyed waves (m190): boosting
// one wave's MFMA delays its peers toward the shared barrier. The LN2
// prefetch (nw2v/nb2v in MLP chunk-3's idle slot) is mechanistically
// identical to the proven b1/pbv/xv6 prefetch wins and is kept.
// Math order per value unchanged -> absmax canary 0.09375.
// Evidence trail: R23 -6%, R24 -2%, R25 -1%, R26 -4%, R27 -2%, R28 +1.5%
// (setprio revert); R18 TLP null, R19 VALU null, R21 LDS-op null.
// MFMA 16x16x32 bf16: A[m][k]: m=l15,k=lg*8+i ; B[k][n]: n=l15,k=lg*8+i
//                     C[m][n]: n=l15, m=lg*4+r   (validated rounds 2-28)
// ---------------------------------------------------------------------------

constexpr int WIN=8, CD=96, RH=128, RW=128, SHF=4;

// LDS layout in shorts
constexpr int KN_S=40, VT_S=72, WB_S=104;
constexpr int OFF_KN=0;                 // kn [64][40]            0..2560
constexpr int OFF_VT=2560;              // vt [32][72]            ..4864
constexpr int PAN_SH=10240;             // padded panel: 96*104 (+256 pad) shorts
constexpr int OFF_WB0=4864;             // panel buf0             ..15104
constexpr int OFF_WB1=15104;            // panel buf1             ..25344
constexpr int LDS_SHORTS=25344;
constexpr int LDS_BYTES = LDS_SHORTS*2; // 50688 B -> 3 blocks/CU

typedef float f32x4 __attribute__((ext_vector_type(4)));
typedef short s16x8 __attribute__((ext_vector_type(8)));
typedef short s16x4 __attribute__((ext_vector_type(4)));
typedef int   i32x2 __attribute__((ext_vector_type(2)));
typedef int   i32x4 __attribute__((ext_vector_type(4)));
typedef unsigned int u32x2 __attribute__((ext_vector_type(2)));

#define MFMA16(a,b,c) __builtin_amdgcn_mfma_f32_16x16x32_bf16((a),(b),(c),0,0,0)

#if __has_builtin(__builtin_amdgcn_permlane32_swap) && __has_builtin(__builtin_amdgcn_permlane16_swap)
#define HAVE_PLSWAP 1
#else
#define HAVE_PLSWAP 0
#endif

// raw hardware 2^x (v_exp_f32). exp2f() is the precise libm version with
// multi-op edge handling -- see R25 post-mortem (VALUBusy 45->57%).
__device__ __forceinline__ float fexp2(float x) {
#if __has_builtin(__builtin_amdgcn_exp2f)
    return __builtin_amdgcn_exp2f(x);
#else
    return exp2f(x);
#endif
}

// RAW barrier without the implicit vmcnt(0) drain (panel prefetch stays
// in flight). lgkmcnt(0): this wave's ds_writes complete; s_barrier: sync.
#define RAW_LDS_BARRIER() do { \
    asm volatile("s_waitcnt lgkmcnt(0)" ::: "memory"); \
    __builtin_amdgcn_s_barrier(); \
    asm volatile("" ::: "memory"); } while (0)

__device__ __forceinline__ short f2bf(float f) {
    __bf16 b = (__bf16)f;
    return __builtin_bit_cast(short, b);
}
__device__ __forceinline__ s16x8 ld8(const short* p) {
    return *reinterpret_cast<const s16x8*>(p);
}
__device__ __forceinline__ s16x4 pack4(float a, float b, float c, float d) {
    s16x4 r; r[0]=f2bf(a); r[1]=f2bf(b); r[2]=f2bf(c); r[3]=f2bf(d);
    return r;
}
__device__ __forceinline__ s16x8 abf_from_f32(const float* p) {
    const f32x4* q = reinterpret_cast<const f32x4*>(p);
    f32x4 a = q[0], b = q[1];
    s16x8 r;
    r[0]=f2bf(a[0]); r[1]=f2bf(a[1]); r[2]=f2bf(a[2]); r[3]=f2bf(a[3]);
    r[4]=f2bf(b[0]); r[5]=f2bf(b[1]); r[6]=f2bf(b[2]); r[7]=f2bf(b[3]);
    return r;
}

#if HAVE_PLSWAP
__device__ __forceinline__ void plswap32(unsigned &a, unsigned &b) {
    u32x2 r = __builtin_amdgcn_permlane32_swap(a, b, false, false);
    a = r[0]; b = r[1];
}
__device__ __forceinline__ void plswap16(unsigned &a, unsigned &b) {
    u32x2 r = __builtin_amdgcn_permlane16_swap(a, b, false, false);
    a = r[0]; b = r[1];
}
#endif

// wave-local lg-transpose: p0,p1 hold v[base+{0,16}+lg*4+rr] (packed bf16);
// returns B-fragment f[i] = v[base+lg*8+i] for this lane's lg.
__device__ __forceinline__ s16x8 xposeT(s16x4 p0, s16x4 p1, int l) {
    i32x2 q0 = __builtin_bit_cast(i32x2, p0);
    i32x2 q1 = __builtin_bit_cast(i32x2, p1);
#if HAVE_PLSWAP
    (void)l;
    unsigned a0 = (unsigned)q0[0], a1 = (unsigned)q0[1];
    unsigned b0 = (unsigned)q1[0], b1 = (unsigned)q1[1];
    plswap32(a0, b0);
    plswap32(a1, b1);
    plswap16(a0, b0);
    plswap16(a1, b1);
    i32x4 w; w[0]=(int)a0; w[1]=(int)a1; w[2]=(int)b0; w[3]=(int)b1;
    return __builtin_bit_cast(s16x8, w);
#else
    const int l15 = l & 15, lg = l >> 4;
    const int L1 = l15 + (((2*lg  )&3)<<4);
    const int L2 = l15 + (((2*lg+1)&3)<<4);
    const bool lo = (lg & 2) == 0;
    int a0 = __shfl(q0[0], L1), b0 = __shfl(q1[0], L1);
    int a1 = __shfl(q0[1], L1), b1 = __shfl(q1[1], L1);
    int a2 = __shfl(q0[0], L2), b2 = __shfl(q1[0], L2);
    int a3 = __shfl(q0[1], L2), b3 = __shfl(q1[1], L2);
    i32x4 w;
    w[0] = lo ? a0 : b0;
    w[1] = lo ? a1 : b1;
    w[2] = lo ? a2 : b2;
    w[3] = lo ? a3 : b3;
    return __builtin_bit_cast(s16x8, w);
#endif
}
// reduce across the 4 lg groups (lanes sharing l15), VALU pipe when possible
__device__ __forceinline__ float xsum4(float v) {
#if HAVE_PLSWAP
    unsigned a = __builtin_bit_cast(unsigned, v), b = a;
    plswap16(a, b);
    float s = __builtin_bit_cast(float, a) + __builtin_bit_cast(float, b);
    unsigned c = __builtin_bit_cast(unsigned, s), d = c;
    plswap32(c, d);
    return __builtin_bit_cast(float, c) + __builtin_bit_cast(float, d);
#else
    v += __shfl_xor(v,16); v += __shfl_xor(v,32); return v;
#endif
}
__device__ __forceinline__ float xmax4(float v) {
#if HAVE_PLSWAP
    unsigned a = __builtin_bit_cast(unsigned, v), b = a;
    plswap16(a, b);
    float s = fmaxf(__builtin_bit_cast(float, a), __builtin_bit_cast(float, b));
    unsigned c = __builtin_bit_cast(unsigned, s), d = c;
    plswap32(c, d);
    return fmaxf(__builtin_bit_cast(float, c), __builtin_bit_cast(float, d));
#else
    v = fmaxf(v, __shfl_xor(v,16)); v = fmaxf(v, __shfl_xor(v,32)); return v;
#endif
}
__device__ __forceinline__ int region_id(int hh, int ww) {
    int rr = (hh < RH-WIN) ? 0 : ((hh < RH-SHF) ? 1 : 2);
    int rc = (ww < RW-WIN) ? 0 : ((ww < RW-SHF) ? 1 : 2);
    return rr*3 + rc;
}
// GELU with log2e folded into the polynomial (raw v_exp_f32)
__device__ __forceinline__ float gelu_f(float h) {
    float u = h * (2.3022089f + 0.10294356f * h * h);
    float e = fexp2(-u);
    return h * __builtin_amdgcn_rcpf(1.f + e);
}

// async stage of one padded 20480-B panel into LDS (linear dest, 20 chunks)
__device__ __forceinline__ void stage_panel(const short* __restrict__ pan,
                                            short* dst, int wv, int l) {
    const char* g = (const char*)pan + l*16;
    char* d = (char*)dst;
    #pragma unroll
    for (int k = 0; k < 5; ++k) {
        int i = wv + k*4;                 // exactly 20 chunks of 1024 B / 4 waves
        __builtin_amdgcn_global_load_lds(
            (const __attribute__((address_space(1))) unsigned int*)(g + i*1024),
            (__attribute__((address_space(3))) unsigned int*)(d + i*1024),
            16, 0, 0);
    }
}

// ---------------------------------------------------------------------------
__global__ __launch_bounds__(256) void cpb_kernel(
    const float* __restrict__ w1, const float* __restrict__ b1,
    const float* __restrict__ w2, float* __restrict__ rpb)
{
    int g = blockIdx.x*256 + threadIdx.x;
    if (g >= 225*3) return;
    int e = g/3, h = g - e*3;
    int a = e/15, bb = e - a*15;
    float z0 = (float)(a-7) * (8.0f/7.0f);
    float z1 = (float)(bb-7) * (8.0f/7.0f);
    float s0 = (z0>0.f)?1.f:((z0<0.f)?-1.f:0.f);
    float s1 = (z1>0.f)?1.f:((z1<0.f)?-1.f:0.f);
    float t0 = s0 * log2f(fabsf(z0)+1.f) * (1.f/3.f);
    float t1 = s1 * log2f(fabsf(z1)+1.f) * (1.f/3.f);
    float acc = 0.f;
    for (int k = 0; k < 512; ++k) {
        float hv = t0*w1[2*k] + t1*w1[2*k+1] + b1[k];
        hv = fmaxf(hv, 0.f);
        acc += hv * w2[h*512 + k];
    }
    rpb[g] = 16.f / (1.f + __expf(-acc));
}

// biasT pre-scaled by log2e (softmax computed in exp2 domain)
__global__ __launch_bounds__(256) void biasbuild_kernel(
    const float* __restrict__ rpb, float* __restrict__ biasT)
{
    int g = blockIdx.x*256 + threadIdx.x;     // 12288
    if (g >= 3*64*64) return;
    int h = g >> 12, rem = g & 4095, i = rem >> 6, j = rem & 63;
    int ih = i>>3, iw = i&7, jh = j>>3, jw = j&7;
    int idx = (ih-jh+7)*15 + (iw-jw+7);
    biasT[g] = rpb[idx*3 + h] * 1.44269504f;
}

// prepack 12 padded panels (rows of WB_S=104 shorts, 96 valid cols)
__global__ __launch_bounds__(256) void wcvt_kernel(
    const float* __restrict__ qkvw, const float* __restrict__ projw,
    const float* __restrict__ w1,   const float* __restrict__ w2,
    short* __restrict__ wpan)
{
    int i = blockIdx.x*256 + threadIdx.x;     // 110592 exact (432 blocks)
    if (i >= 12*9216) return;
    int p = i / 9216;
    int rem = i - p*9216;
    int r = rem / 96;
    int col = rem - r*96;
    float v;
    if (p < 3)        v = qkvw[((r>>5)*96 + p*32 + (r&31))*96 + col];
    else if (p == 3)  v = projw[r*96 + col];
    else if (((p-4)&1) == 0) { int c = (p-4)>>1; v = w1[(c*96 + r)*96 + col]; }
    else              { int c = (p-4)>>1; v = w2[r*384 + c*96 + col]; }
    wpan[p*PAN_SH + r*WB_S + col] = f2bf(v);
}

// ---------------------------------------------------------------------------
__global__ __launch_bounds__(256,3) void fused_kernel(
    const float* __restrict__ x,
    const float* __restrict__ n1w, const float* __restrict__ n1b,
    const float* __restrict__ qb,  const float* __restrict__ vb,
    const float* __restrict__ lgs, const float* __restrict__ pb,
    const float* __restrict__ n2w, const float* __restrict__ n2b,
    const float* __restrict__ b1,  const float* __restrict__ b2,
    const float* __restrict__ biasT,
    const short* __restrict__ wpan,   // 12 padded panels
    float* __restrict__ out)
{
    extern __shared__ __align__(16) short smem[];
    short* kn  = smem + OFF_KN;
    short* vt  = smem + OFF_VT;
    short* wb0 = smem + OFF_WB0;
    short* wb1 = smem + OFF_WB1;

    const int t = threadIdx.x;
    const int l = t & 63;
    const int wv = t >> 6;
    const int l15 = l & 15;
    const int lg  = l >> 4;

    const int wid = blockIdx.x;
    const int b = wid >> 8, wi = wid & 255, wh = wi >> 4, ww = wi & 15;
    const float* xb = x + (size_t)b * (RH*RW*CD);

    // lane's own token and its global (gather == scatter) position
    const int arow = wv*16 + l15;
    const int ahs = (wh*WIN + (arow>>3) + SHF) & (RH-1);
    const int aws = (ww*WIN + (arow&7)  + SHF) & (RW-1);
    const unsigned go = ((unsigned)(b << 14) + ahs*RW + aws) * CD;
    const float* xrow = xb + (ahs*RW + aws)*CD;
    s16x8 xa[3];
    #pragma unroll
    for (int kt = 0; kt < 3; ++kt) xa[kt] = abf_from_f32(xrow + kt*32 + lg*8);

    // shift-mask (log2e-scaled, exp2 domain): i = arow, j = mt*16+lg*4+rr
    f32x4 maskv[4];
    {
        int regi = region_id(wh*WIN + (arow>>3), ww*WIN + (arow&7));
        #pragma unroll
        for (int mt = 0; mt < 4; ++mt)
            #pragma unroll
            for (int rr = 0; rr < 4; ++rr) {
                int j = mt*16 + lg*4 + rr;
                int regj = region_id(wh*WIN + (j>>3), ww*WIN + (j&7));
                maskv[mt][rr] = (regi != regj) ? -144.2695041f : 0.f;
            }
    }

    // head-0 S^T C-in (bias+mask) prefetched before any barrier
    f32x4 bvmc[4], bvmn[4];
    {
        const float* bh = biasT + arow*64;
        #pragma unroll
        for (int mt = 0; mt < 4; ++mt) {
            f32x4 bv = *reinterpret_cast<const f32x4*>(bh + mt*16 + lg*4);
            #pragma unroll
            for (int rr = 0; rr < 4; ++rr) bvmc[mt][rr] = bv[rr] + maskv[mt][rr];
        }
    }

    // QKV compute: reads weight panel (LDS) + xa regs; biases as C-in.
    auto qkv_compute = [&](const short* wbuf, int hh,
                           f32x4 qc[2], f32x4 kc[2], f32x4 vc[2]) {
        #pragma unroll
        for (int sec = 0; sec < 3; ++sec) {
            #pragma unroll
            for (int nt = 0; nt < 2; ++nt) {
                f32x4 c;
                if (sec==0)      c = *reinterpret_cast<const f32x4*>(qb + hh*32 + nt*16 + lg*4);
                else if (sec==2) c = *reinterpret_cast<const f32x4*>(vb + hh*32 + nt*16 + lg*4);
                else             c = (f32x4){0.f,0.f,0.f,0.f};
                const short* wp = wbuf + (sec*32 + nt*16 + l15)*WB_S;
                #pragma unroll
                for (int kt = 0; kt < 3; ++kt)
                    c = MFMA16(ld8(wp + kt*32 + lg*8), xa[kt], c);
                if (sec==0) qc[nt]=c; else if (sec==1) kc[nt]=c; else vc[nt]=c;
            }
        }
    };
    // norms over d (paired trees + cross-group reduce); scq carries log2e
    auto qk_norms = [&](const f32x4 qc[2], const f32x4 kc[2], int hh,
                        float &scq, float &sck) {
        float sq = ((qc[0][0]*qc[0][0] + qc[0][1]*qc[0][1])
                  + (qc[0][2]*qc[0][2] + qc[0][3]*qc[0][3]))
                 + ((qc[1][0]*qc[1][0] + qc[1][1]*qc[1][1])
                  + (qc[1][2]*qc[1][2] + qc[1][3]*qc[1][3]));
        float sk = ((kc[0][0]*kc[0][0] + kc[0][1]*kc[0][1])
                  + (kc[0][2]*kc[0][2] + kc[0][3]*kc[0][3]))
                 + ((kc[1][0]*kc[1][0] + kc[1][1]*kc[1][1])
                  + (kc[1][2]*kc[1][2] + kc[1][3]*kc[1][3]));
        sq = xsum4(sq);
        sk = xsum4(sk);
        float ls = 1.44269504f * __expf(fminf(lgs[hh], 4.60517019f));
        scq = ls * __builtin_amdgcn_rsqf(fmaxf(sq, 1e-24f));
        sck =      __builtin_amdgcn_rsqf(fmaxf(sk, 1e-24f));
    };

    // ================= prologue: P0,P1 staged; QKV(0); knvt(0) =================
    stage_panel(wpan,          wb0, wv, l);            // P0 -> buf0 (async)
    stage_panel(wpan + PAN_SH, wb1, wv, l);            // P1 -> buf1 (async)
    __syncthreads();                                   // drain P0+P1

    s16x4 qp0, qp1;                                    // head-h q packed
    {
        f32x4 qc[2], kc[2], vc[2];
        qkv_compute(wb0, 0, qc, kc, vc);
        float scq, sck;
        qk_norms(qc, kc, 0, scq, sck);
        qp0 = pack4(qc[0][0]*scq, qc[0][1]*scq, qc[0][2]*scq, qc[0][3]*scq);
        qp1 = pack4(qc[1][0]*scq, qc[1][1]*scq, qc[1][2]*scq, qc[1][3]*scq);
        #pragma unroll
        for (int nt = 0; nt < 2; ++nt) {
            *reinterpret_cast<s16x4*>(kn + arow*KN_S + nt*16 + lg*4) =
                pack4(kc[nt][0]*sck, kc[nt][1]*sck, kc[nt][2]*sck, kc[nt][3]*sck);
            #pragma unroll
            for (int rr = 0; rr < 4; ++rr)
                vt[(nt*16 + lg*4 + rr)*VT_S + arow] = f2bf(vc[nt][rr]);
        }
    }
    RAW_LDS_BARRIER();                                 // knvt(0) visible

    s16x4 aop[6];                                      // attn out, packed bf16
    f32x4 xv6[6];                                      // x residual (head-2 prefetch)
    f32x4 pbv[6];                                      // proj bias (head-2 prefetch)
    f32x4 nw1v[6], nb1v[6];                            // LN1 w/b (head-2 prefetch)
    s16x8 aB[3];                                       // proj A-fragments

    // ================= attention heads (software-pipelined) =================
    #pragma unroll
    for (int h = 0; h < 3; ++h) {
        // stage P(h+2): wb[h&1]'s readers (QKV(h)) all passed the last
        // s_barrier (WAR safe). Drained by a later full __syncthreads().
        stage_panel(wpan + (h+2)*PAN_SH, (h&1) ? wb1 : wb0, wv, l);

        // ---- S^T = mfma(kn, qA, bias+mask prefetched): C[m=j][n=i=arow] ----
        s16x8 qA = xposeT(qp0, qp1, l);
        f32x4 st[4];
        #pragma unroll
        for (int mt = 0; mt < 4; ++mt)
            st[mt] = MFMA16(ld8(kn + (mt*16 + l15)*KN_S + lg*8), qA, bvmc[mt]);

        // ---- PIPELINE filler for the softmax dependency-stall window ----
        f32x4 nqc[2], nkc[2], nvc[2];
        if (h < 2) {
            // QKV(h+1) compute (independent of kn/vt) + bvm(h+1) prefetch
            qkv_compute((h&1) ? wb0 : wb1, h+1, nqc, nkc, nvc);
            const float* bh2 = biasT + (h+1)*4096 + arow*64;
            #pragma unroll
            for (int mt = 0; mt < 4; ++mt) {
                f32x4 bv = *reinterpret_cast<const f32x4*>(bh2 + mt*16 + lg*4);
                #pragma unroll
                for (int rr = 0; rr < 4; ++rr) bvmn[mt][rr] = bv[rr] + maskv[mt][rr];
            }
        } else {
            // head 2: issue x-residual + proj-bias + LN1 w/b loads (consumed
            // at proj/LN1; only RAW barriers -- no vmcnt drain -- between
            // here and use) + proj A-fragment xposes for heads 0/1.
            #pragma unroll
            for (int nt = 0; nt < 6; ++nt) {
                xv6[nt]  = *reinterpret_cast<const f32x4*>(x + go + nt*16 + lg*4);
                pbv[nt]  = *reinterpret_cast<const f32x4*>(pb + nt*16 + lg*4);
                nw1v[nt] = *reinterpret_cast<const f32x4*>(n1w + nt*16 + lg*4);
                nb1v[nt] = *reinterpret_cast<const f32x4*>(n1b + nt*16 + lg*4);
            }
            aB[0] = xposeT(aop[0], aop[1], l);
            aB[1] = xposeT(aop[2], aop[3], l);
        }

        // ---- softmax over j (exp2 domain, raw v_exp_f32) ----
        float m0 = fmaxf(fmaxf(st[0][0],st[0][1]), fmaxf(st[0][2],st[0][3]));
        float m1 = fmaxf(fmaxf(st[1][0],st[1][1]), fmaxf(st[1][2],st[1][3]));
        float m2 = fmaxf(fmaxf(st[2][0],st[2][1]), fmaxf(st[2][2],st[2][3]));
        float m3 = fmaxf(fmaxf(st[3][0],st[3][1]), fmaxf(st[3][2],st[3][3]));
        float mx = xmax4(fmaxf(fmaxf(m0,m1), fmaxf(m2,m3)));
        float sp[4];
        #pragma unroll
        for (int mt = 0; mt < 4; ++mt) {
            #pragma unroll
            for (int rr = 0; rr < 4; ++rr)
                st[mt][rr] = fexp2(st[mt][rr] - mx);
            sp[mt] = (st[mt][0] + st[mt][1]) + (st[mt][2] + st[mt][3]);
        }
        float sm = xsum4((sp[0] + sp[1]) + (sp[2] + sp[3]));
        float inv = __builtin_amdgcn_rcpf(sm);

        // ---- retire head h+1 norms EARLY (independent of P; shortens the
        //      post-PV tail before the convoy-limiting __syncthreads) ----
        float sck_n = 0.f;
        s16x4 nq0, nq1;
        if (h < 2) {
            float scq_n;
            qk_norms(nqc, nkc, h+1, scq_n, sck_n);
            nq0 = pack4(nqc[0][0]*scq_n, nqc[0][1]*scq_n, nqc[0][2]*scq_n, nqc[0][3]*scq_n);
            nq1 = pack4(nqc[1][0]*scq_n, nqc[1][1]*scq_n, nqc[1][2]*scq_n, nqc[1][3]*scq_n);
        }

        // ---- P packed UNNORMALIZED; inv folded into aop pack ----
        s16x4 pw[4];
        #pragma unroll
        for (int mt = 0; mt < 4; ++mt)
            pw[mt] = pack4(st[mt][0], st[mt][1], st[mt][2], st[mt][3]);

        // ---- PV^T = mfma(vt, P-frag): C[m=d][n=token] -> packed regs ----
        s16x8 pB0 = xposeT(pw[0], pw[1], l);
        s16x8 pB1 = xposeT(pw[2], pw[3], l);
        #pragma unroll
        for (int nt2 = 0; nt2 < 2; ++nt2) {
            f32x4 o = {0.f,0.f,0.f,0.f};
            o = MFMA16(ld8(vt + (nt2*16+l15)*VT_S + 0  + lg*8), pB0, o);
            o = MFMA16(ld8(vt + (nt2*16+l15)*VT_S + 32 + lg*8), pB1, o);
            aop[h*2 + nt2] = pack4(o[0]*inv, o[1]*inv, o[2]*inv, o[3]*inv);
        }

        // ---- retire: barrier, then knvt(h+1) writes ----
        if (h < 2) {
            __syncthreads();               // all waves' S/PV(h) kn/vt reads done;
                                           // also drains P(h+2) (full phase old)
            #pragma unroll
            for (int nt = 0; nt < 2; ++nt) {
                *reinterpret_cast<s16x4*>(kn + arow*KN_S + nt*16 + lg*4) =
                    pack4(nkc[nt][0]*sck_n, nkc[nt][1]*sck_n,
                          nkc[nt][2]*sck_n, nkc[nt][3]*sck_n);
                #pragma unroll
                for (int rr = 0; rr < 4; ++rr)
                    vt[(nt*16 + lg*4 + rr)*VT_S + arow] = f2bf(nvc[nt][rr]);
            }
            RAW_LDS_BARRIER();             // knvt(h+1) visible; panel stage
                                           // stays in flight (no vmcnt drain)
            qp0 = nq0; qp1 = nq1;
            #pragma unroll
            for (int mt = 0; mt < 4; ++mt) bvmc[mt] = bvmn[mt];
        }
    }

    // ================= proj^T + LN1 + residual (in-register) =================
    // P3 (proj) landed in wb1 (staged iter1, drained at iter1's syncthreads);
    // P4 (w1 c0) staged at iter2 top, drains at the MLP-top syncthreads.
    aB[2] = xposeT(aop[4], aop[5], l);
    f32x4 pc[6];
    #pragma unroll
    for (int nt = 0; nt < 6; ++nt) {
        f32x4 c = pbv[nt];                             // prefetched proj bias
        const short* wp = wb1 + (nt*16 + l15)*WB_S;
        #pragma unroll
        for (int kt = 0; kt < 3; ++kt)
            c = MFMA16(ld8(wp + kt*32 + lg*8), aB[kt], c);
        pc[nt] = c;                                    // C[m=outc][n=token=arow]
    }

    f32x4 x1v[6];                                      // f32 residual in regs
    s16x4 x1p[6];                                      // packed bf16 x1
    {
        float sA=0.f, sB=0.f, s2A=0.f, s2B=0.f;
        #pragma unroll
        for (int nt = 0; nt < 6; ++nt) {
            f32x4 v = pc[nt];
            float ps  = (v[0]+v[1]) + (v[2]+v[3]);
            float ps2 = (v[0]*v[0]+v[1]*v[1]) + (v[2]*v[2]+v[3]*v[3]);
            if (nt & 1) { sB += ps; s2B += ps2; } else { sA += ps; s2A += ps2; }
        }
        float s = xsum4(sA + sB), s2 = xsum4(s2A + s2B);
        float mu  = s * (1.f/96.f);
        float var = s2 * (1.f/96.f) - mu*mu;
        float rstd = __builtin_amdgcn_rsqf(var + 1e-5f);
        #pragma unroll
        for (int nt = 0; nt < 6; ++nt) {
            f32x4 v;
            #pragma unroll
            for (int rr = 0; rr < 4; ++rr)
                v[rr] = xv6[nt][rr] + (pc[nt][rr] - mu)*rstd*nw1v[nt][rr] + nb1v[nt][rr];
            x1v[nt] = v;
            x1p[nt] = pack4(v[0], v[1], v[2], v[3]);
        }
    }

    // ================= MLP (swapped G1/G2, in-register h) =================
    s16x8 x1B[3];
    #pragma unroll
    for (int kt = 0; kt < 3; ++kt)
        x1B[kt] = xposeT(x1p[2*kt], x1p[2*kt+1], l);

    f32x4 b1v[6];                                      // G1 C-in, chunk 0
    #pragma unroll
    for (int nt = 0; nt < 6; ++nt)
        b1v[nt] = *reinterpret_cast<const f32x4*>(b1 + nt*16 + lg*4);

    f32x4 oa[6];
    #pragma unroll
    for (int nt = 0; nt < 6; ++nt)                     // b2 as G2 C-in
        oa[nt] = *reinterpret_cast<const f32x4*>(b2 + nt*16 + lg*4);

    f32x4 nw2v[6], nb2v[6];                            // LN2 w/b (chunk-3 prefetch)

    for (int c = 0; c < 4; ++c) {
        __syncthreads();                    // w1 chunk landed (vmcnt WANTED)
        stage_panel(wpan + (5+2*c)*PAN_SH, wb1, wv, l);
        // G1^T: C[m=hid][n=token], prefetched b1 as C-in -> GELU -> packed
        s16x4 hp[6];
        #pragma unroll
        for (int nt = 0; nt < 6; ++nt) {
            f32x4 a = b1v[nt];
            const short* wp = wb0 + (nt*16 + l15)*WB_S;
            #pragma unroll
            for (int kt = 0; kt < 3; ++kt)
                a = MFMA16(ld8(wp + kt*32 + lg*8), x1B[kt], a);
            hp[nt] = pack4(gelu_f(a[0]), gelu_f(a[1]), gelu_f(a[2]), gelu_f(a[3]));
        }
        // prefetch b1 for next chunk (overlaps GELU; drained at next sync);
        // chunk 3: prefetch LN2 params instead (last uncovered window)
        if (c < 3) {
            #pragma unroll
            for (int nt = 0; nt < 6; ++nt)
                b1v[nt] = *reinterpret_cast<const f32x4*>(b1 + (c+1)*96 + nt*16 + lg*4);
        } else {
            #pragma unroll
            for (int nt = 0; nt < 6; ++nt) {
                nw2v[nt] = *reinterpret_cast<const f32x4*>(n2w + nt*16 + lg*4);
                nb2v[nt] = *reinterpret_cast<const f32x4*>(n2b + nt*16 + lg*4);
            }
        }
        __syncthreads();                    // w2 chunk landed (vmcnt WANTED)
        if (c < 3) stage_panel(wpan + (6+2*c)*PAN_SH, wb0, wv, l);
        // G2^T accumulate: C[m=outc][n=token]
        s16x8 hB[3];
        #pragma unroll
        for (int kt = 0; kt < 3; ++kt)
            hB[kt] = xposeT(hp[2*kt], hp[2*kt+1], l);
        #pragma unroll
        for (int nt = 0; nt < 6; ++nt) {
            const short* wp = wb1 + (nt*16 + l15)*WB_S;
            #pragma unroll
            for (int kt = 0; kt < 3; ++kt)
                oa[nt] = MFMA16(ld8(wp + kt*32 + lg*8), hB[kt], oa[nt]);
        }
    }

    // ---- LN2 (+b2 already in oa), +x1 residual, f32x4 stores ----
    {
        float sA=0.f, sB=0.f, s2A=0.f, s2B=0.f;
        #pragma unroll
        for (int nt = 0; nt < 6; ++nt) {
            f32x4 v = oa[nt];
            float ps  = (v[0]+v[1]) + (v[2]+v[3]);
            float ps2 = (v[0]*v[0]+v[1]*v[1]) + (v[2]*v[2]+v[3]*v[3]);
            if (nt & 1) { sB += ps; s2B += ps2; } else { sA += ps; s2A += ps2; }
        }
        float s = xsum4(sA + sB), s2 = xsum4(s2A + s2B);
        float mu  = s * (1.f/96.f);
        float var = s2 * (1.f/96.f) - mu*mu;
        float rstd = __builtin_amdgcn_rsqf(var + 1e-5f);
        #pragma unroll
        for (int nt = 0; nt < 6; ++nt) {
            f32x4 res;
            #pragma unroll
            for (int rr = 0; rr < 4; ++rr)
                res[rr] = x1v[nt][rr] + (oa[nt][rr] - mu)*rstd*nw2v[nt][rr] + nb2v[nt][rr];
            *reinterpret_cast<f32x4*>(out + go + nt*16 + lg*4) = res;
        }
    }
}

// ---------------------------------------------------------------------------
extern "C" void kernel_launch(void* const* d_in, const int* in_sizes, int n_in,
                              void* d_out, int out_size, void* d_ws, size_t ws_size,
                              hipStream_t stream) {
    const float* x       = (const float*)d_in[0];
    const float* norm1_w = (const float*)d_in[1];
    const float* norm1_b = (const float*)d_in[2];
    const float* qkv_w   = (const float*)d_in[3];
    const float* q_bias  = (const float*)d_in[4];
    const float* v_bias  = (const float*)d_in[5];
    const float* lgs     = (const float*)d_in[6];
    const float* cpb_w1  = (const float*)d_in[7];
    const float* cpb_b1  = (const float*)d_in[8];
    const float* cpb_w2  = (const float*)d_in[9];
    const float* proj_w  = (const float*)d_in[10];
    const float* proj_b  = (const float*)d_in[11];
    const float* norm2_w = (const float*)d_in[12];
    const float* norm2_b = (const float*)d_in[13];
    const float* mlp_w1  = (const float*)d_in[14];
    const float* mlp_b1  = (const float*)d_in[15];
    const float* mlp_w2  = (const float*)d_in[16];
    const float* mlp_b2  = (const float*)d_in[17];

    char* wsb = (char*)d_ws;
    float* rpbTab = (float*)wsb;                     // 675 f32   @ 0
    float* biasT  = (float*)(wsb + 4096);            // 12288 f32 @ 4096
    short* wpan   = (short*)(wsb + 53248);           // 12 padded panels (240 KB)

    float* out = (float*)d_out;

    hipFuncSetAttribute(reinterpret_cast<const void*>(fused_kernel),
                        hipFuncAttributeMaxDynamicSharedMemorySize, LDS_BYTES);

    cpb_kernel<<<3, 256, 0, stream>>>(cpb_w1, cpb_b1, cpb_w2, rpbTab);
    biasbuild_kernel<<<48, 256, 0, stream>>>(rpbTab, biasT);
    wcvt_kernel<<<432, 256, 0, stream>>>(qkv_w, proj_w, mlp_w1, mlp_w2, wpan);
    fused_kernel<<<8192, 256, LDS_BYTES, stream>>>(x, norm1_w, norm1_b,
                                                   q_bias, v_bias, lgs, proj_b,
                                                   norm2_w, norm2_b, mlp_b1, mlp_b2,
                                                   biasT, wpan, out);
}